// Round 2
// baseline (541.404 us; speedup 1.0000x reference)
//
#include <hip/hip_runtime.h>
#include <math.h>

// KoLeo loss: dist_i = sqrt(2 - 2*max_{j!=i} <fhat_i, fhat_j>); loss = -mean(log(dist+1e-8))
// R11: barrier-free register-direct Gram row/col-max via MX-scaled fp8 MFMA
// (16x16x128 f8f6f4, unit scales). Evidence from R9/R10: both prior structures
// were LDS-pipe-bound (R9: 4.2 GB LDS reads ~= 81 us/CU floor; R10 lockstep
// added stalls, MfmaUtil 28% with MFMA busy-time pinned at the 59 us floor).
// Data is 16 MB fp8 -> fully L3-resident, L2-warm. This version deletes LDS
// staging entirely: each wave streams its A/B fragments global->VGPR (L2),
// accumulates 128x64 output in AGPRs, no __syncthreads in the main loop.
// 8 waves/block (2x4 grid), 256^2 block tile, triangular launch, XCD swizzle.
// In-place fragment reload: afr[mi] reloaded right after its 4 MFMAs issue
// (WAR is issue-ordered), bfr at tile end; last K-tile peeled (no dead loads).
// Regs: acc 128 + afr 64 + bfr 32 + addr ~15 -> fits 2 waves/SIMD (<=256).
// Features pre-scaled x16 before e4m3 cast; raw dots carry x256, folded out in
// row_reduce (max is monotone). Each tile yields row-max AND col-max.

#define N_ROWS 16384
#define DIM 1024
#define BT 256
#define NT (N_ROWS / BT)          // 64
#define NKT (DIM / 128)           // 8 K-tiles (128 fp8 elements each)
#define NBLK (NT * (NT + 1) / 2)  // 2080 (divisible by 8 -> simple XCD swizzle)

typedef int   i32x4 __attribute__((ext_vector_type(4)));
typedef int   i32x8 __attribute__((ext_vector_type(8)));
typedef float f32x4 __attribute__((ext_vector_type(4)));

// ---------------------------------------------------------------- normalize
__global__ __launch_bounds__(256) void normalize_kernel(
    const float* __restrict__ in, unsigned int* __restrict__ outp) {
  const int row = blockIdx.x;
  const int t = threadIdx.x;  // 256 threads x 4 floats
  const float4 v = ((const float4*)(in + (size_t)row * DIM))[t];
  float ss = v.x * v.x + v.y * v.y + v.z * v.z + v.w * v.w;
#pragma unroll
  for (int s = 1; s < 64; s <<= 1) ss += __shfl_xor(ss, s, 64);
  __shared__ float wsum[4];
  const int wave = t >> 6, lane = t & 63;
  if (lane == 0) wsum[wave] = ss;
  __syncthreads();
  const float tot = wsum[0] + wsum[1] + wsum[2] + wsum[3];
  const float scale = 16.f / fmaxf(sqrtf(tot), 1e-12f);
  unsigned int p = __builtin_amdgcn_cvt_pk_fp8_f32(v.x * scale, v.y * scale, 0, false);
  p = __builtin_amdgcn_cvt_pk_fp8_f32(v.z * scale, v.w * scale, p, true);
  outp[(size_t)row * (DIM / 4) + t] = p;
}

// Load one 32-byte fragment (lane's A or B operand) as two dwordx4.
#define LOADF(dst, off)                                             \
  do {                                                              \
    i32x4 _lo = *(const i32x4*)(F + (off));                         \
    i32x4 _hi = *(const i32x4*)(F + (off) + 16);                    \
    dst = __builtin_shufflevector(_lo, _hi, 0, 1, 2, 3, 4, 5, 6, 7); \
  } while (0)

#define MFMA_ROW(MI)                                                          \
  do {                                                                       \
    _Pragma("unroll") for (int ni = 0; ni < 4; ++ni) {                       \
      acc[(MI)][ni] = __builtin_amdgcn_mfma_scale_f32_16x16x128_f8f6f4(      \
          afr[(MI)], bfr[ni], acc[(MI)][ni], 0, 0,                           \
          0, 0x7F7F7F7F, 0, 0x7F7F7F7F); /* unit e8m0 scales */              \
    }                                                                        \
  } while (0)

// -------------------------------------------------- Gram row/col-max GEMM
__global__ __launch_bounds__(512, 2) void gemm_rowmax(
    const unsigned char* __restrict__ F, float* __restrict__ partial) {
  // XCD-chunked bijective swizzle (2080 % 8 == 0), then triangular decode
  int bid = blockIdx.x;
  bid = (bid & 7) * (NBLK / 8) + (bid >> 3);
  double disc = (double)(2 * NT + 1) * (2 * NT + 1) - 8.0 * (double)bid;
  int it = (int)(((2 * NT + 1) - sqrt(disc)) * 0.5);
  if (it > NT - 1) it = NT - 1;
  while (it > 0 && it * NT - it * (it - 1) / 2 > bid) --it;
  while ((it + 1) * NT - (it + 1) * it / 2 <= bid) ++it;
  const int jt = it + (bid - (it * NT - it * (it - 1) / 2));

  const int ibase = it * BT, jbase = jt * BT;
  const int tid = threadIdx.x;
  const int wave = tid >> 6, lane = tid & 63;
  const int wi = wave >> 2, wj = wave & 3;  // 2x4 wave grid, 128x64 each
  const int quad = lane >> 4, r16 = lane & 15;

  // Per-lane fragment byte offsets (A: 8 row-frags, B: 4 col-frags).
  // Frag layout for 16x16x128 f8f6f4: lane(quad,r16) holds bytes
  // [quad*32, +32) of row r16 -- 32 contiguous bytes, 2x dwordx4.
  unsigned int aoff[8], boff[4];
#pragma unroll
  for (int mi = 0; mi < 8; ++mi)
    aoff[mi] = (unsigned int)(ibase + wi * 128 + mi * 16 + r16) * DIM + quad * 32;
#pragma unroll
  for (int ni = 0; ni < 4; ++ni)
    boff[ni] = (unsigned int)(jbase + wj * 64 + ni * 16 + r16) * DIM + quad * 32;

  f32x4 acc[8][4] = {};  // [mi][ni] 16x16 tiles (AGPR-resident)
  i32x8 afr[8], bfr[4];

  // prologue: K-tile 0 fragments
#pragma unroll
  for (int mi = 0; mi < 8; ++mi) LOADF(afr[mi], aoff[mi]);
#pragma unroll
  for (int ni = 0; ni < 4; ++ni) LOADF(bfr[ni], boff[ni]);

  // main loop: compute tile kt, reload frags for kt+1 in place.
  // afr[mi] reload issues right after its 4 MFMAs (in-order issue makes the
  // WAR safe); bfr reloads at tile end -> ~16 MFMAs of latency cover, and the
  // co-resident wave on the SIMD fills any remaining vmcnt stall.
#pragma unroll 1
  for (int kt = 0; kt < NKT - 1; ++kt) {
#pragma unroll
    for (int mi = 0; mi < 8; ++mi) aoff[mi] += 128;
#pragma unroll
    for (int mi = 0; mi < 8; ++mi) {
      MFMA_ROW(mi);
      LOADF(afr[mi], aoff[mi]);
    }
#pragma unroll
    for (int ni = 0; ni < 4; ++ni) {
      boff[ni] += 128;
      LOADF(bfr[ni], boff[ni]);
    }
  }
  // peeled final K-tile: pure MFMA, no dead loads
#pragma unroll
  for (int mi = 0; mi < 8; ++mi) MFMA_ROW(mi);

  // ---------------- epilogue: row/col max (small dedicated LDS)
  __shared__ float red[BT][4];   // row-max partials over wj
  __shared__ float redc[BT][2];  // col-max partials over wi

  // C/D layout (16x16): col = lane&15, row = quad*4 + reg.
#pragma unroll
  for (int mi = 0; mi < 8; ++mi) {
#pragma unroll
    for (int r = 0; r < 4; ++r) {
      const int rl = wi * 128 + mi * 16 + quad * 4 + r;
      const int rowg = ibase + rl;
      float m = -INFINITY;
#pragma unroll
      for (int ni = 0; ni < 4; ++ni) {
        const int colg = jbase + wj * 64 + ni * 16 + r16;
        const float v = acc[mi][ni][r];
        m = (rowg == colg) ? m : fmaxf(m, v);
      }
#pragma unroll
      for (int s = 1; s < 16; s <<= 1) m = fmaxf(m, __shfl_xor(m, s, 64));
      if (r16 == 0) red[rl][wj] = m;
    }
  }
  if (it != jt) {  // col-max (off-diagonal tiles: no diag elements present)
#pragma unroll
    for (int ni = 0; ni < 4; ++ni) {
      float m = -INFINITY;
#pragma unroll
      for (int mi = 0; mi < 8; ++mi)
#pragma unroll
        for (int r = 0; r < 4; ++r) m = fmaxf(m, acc[mi][ni][r]);
      m = fmaxf(m, __shfl_xor(m, 16, 64));
      m = fmaxf(m, __shfl_xor(m, 32, 64));
      if (quad == 0) redc[wj * 64 + ni * 16 + r16][wi] = m;
    }
  }
  __syncthreads();
  if (tid < BT) {
    const float a = fmaxf(red[tid][0], red[tid][1]);
    const float b = fmaxf(red[tid][2], red[tid][3]);
    partial[(size_t)jt * N_ROWS + ibase + tid] = fmaxf(a, b);
  } else if (it != jt) {
    const int c = tid - BT;
    partial[(size_t)it * N_ROWS + jbase + c] = fmaxf(redc[c][0], redc[c][1]);
  }
}

// ------------------------------------------------------------- reductions
__global__ __launch_bounds__(256) void row_reduce(
    const float* __restrict__ partial, float* __restrict__ blocksum) {
  const int r = blockIdx.x * 256 + threadIdx.x;
  float m = -INFINITY;
  for (int p = 0; p < NT; ++p)
    m = fmaxf(m, partial[(size_t)p * N_ROWS + r]);
  // raw dot carries x256 (features scaled x16): 2 - 2*(m/256) = 2 - m/128
  const float d2 = fmaxf(2.f - m * (1.f / 128.f), 0.f);
  float term = logf(sqrtf(d2) + 1e-8f);
#pragma unroll
  for (int s = 1; s < 64; s <<= 1) term += __shfl_xor(term, s, 64);
  __shared__ float wsum[4];
  const int wave = threadIdx.x >> 6, lane = threadIdx.x & 63;
  if (lane == 0) wsum[wave] = term;
  __syncthreads();
  if (threadIdx.x == 0)
    blocksum[blockIdx.x] = wsum[0] + wsum[1] + wsum[2] + wsum[3];
}

__global__ void finalize(const float* __restrict__ blocksum,
                         float* __restrict__ out) {
  float v = blocksum[threadIdx.x];
#pragma unroll
  for (int s = 1; s < 64; s <<= 1) v += __shfl_xor(v, s, 64);
  if (threadIdx.x == 0) out[0] = -v / (float)N_ROWS;
}

// ---------------------------------------------------------------- launcher
extern "C" void kernel_launch(void* const* d_in, const int* in_sizes, int n_in,
                              void* d_out, int out_size, void* d_ws, size_t ws_size,
                              hipStream_t stream) {
  const float* feats = (const float*)d_in[0];
  float* out = (float*)d_out;
  char* ws = (char*)d_ws;

  // ws: [0,16MB) fp8 features; [16MB,20MB) partial [64][16384] f32; then sums.
  unsigned char* f8 = (unsigned char*)ws;
  float* partial = (float*)(ws + (size_t)N_ROWS * DIM);
  float* blocksum =
      (float*)(ws + (size_t)N_ROWS * DIM + (size_t)NT * N_ROWS * 4);

  normalize_kernel<<<N_ROWS, 256, 0, stream>>>(feats, (unsigned int*)f8);
  gemm_rowmax<<<NBLK, 512, 0, stream>>>(f8, partial);
  row_reduce<<<N_ROWS / 256, 256, 0, stream>>>(partial, blocksum);
  finalize<<<1, 64, 0, stream>>>(blocksum, out);
}

// Round 3
// 313.493 us; speedup vs baseline: 1.7270x; 1.7270x over previous
//
#include <hip/hip_runtime.h>
#include <math.h>

// KoLeo loss: dist_i = sqrt(2 - 2*max_{j!=i} <fhat_i, fhat_j>); loss = -mean(log(dist+1e-8))
// R12: R9's verified 128^2 / 4-wave structure + counted-vmcnt double-buffered
// schedule (T3/T4), sized to keep 2 blocks/CU resident (cross-block overlap --
// the thing R10's 1-block/CU 256^2 port lost). B staged in two bit-permuted
// chunks so LDS-slot order == FIFO consumption order:
//   A (slots=rows, linear)            issued ph1(T-1), consumed ph1(T)
//   B-lo slots 0-63  = rows {0-31,64-95}   issued ph2(T-1), consumed ph1(T)
//   B-hi slots 64-127= rows {32-63,96-127} issued ph2(T-1), consumed ph2(T)
// Wait ladder per tile: vmcnt(2) at ph1 (drains A+B-lo), vmcnt(4) at ph2
// (drains B-hi); invariant 8 loads in flight entering each tile; never 0 in
// the main loop. All staging/read addresses precomputed (R9/R10 recomputed
// ~80 VALU/tile inside the phases). setprio(1) wraps each 8-MFMA cluster.
// 16B-granule XOR swizzle (granule g of row r at physical slot g^(r&7)),
// linear gload_lds dest + pre-swizzled global source (rule #21), verbatim R9.
// Features pre-scaled x16 before e4m3 cast; raw dots carry x256, folded out in
// row_reduce (max is monotone). Each tile yields row-max AND col-max.

#define N_ROWS 16384
#define DIM 1024
#define BT 128
#define BKB 128                   // K bytes per tile (one K=128 MFMA)
#define NKT (DIM / BKB)           // 8
#define NT (N_ROWS / BT)          // 128
#define NBLK (NT * (NT + 1) / 2)  // 8256 (divisible by 8 -> XCD swizzle)

typedef int   i32x4 __attribute__((ext_vector_type(4)));
typedef int   i32x8 __attribute__((ext_vector_type(8)));
typedef float f32x4 __attribute__((ext_vector_type(4)));

__device__ __forceinline__ void async16(const void* g, void* l) {
  __builtin_amdgcn_global_load_lds(
      (__attribute__((address_space(1))) const void*)g,
      (__attribute__((address_space(3))) void*)l, 16, 0, 0);
}

// Raw barrier with compile-time motion fences (rule #18: compiler will hoist
// LDS reads / reg-only MFMA across inline-asm waits and raw barriers).
#define S_BAR()                        \
  do {                                 \
    __builtin_amdgcn_sched_barrier(0); \
    __builtin_amdgcn_s_barrier();      \
    __builtin_amdgcn_sched_barrier(0); \
  } while (0)
#define WAIT_VM(N) asm volatile("s_waitcnt vmcnt(" #N ")" ::: "memory")
#define WAIT_LGKM()                                    \
  do {                                                 \
    asm volatile("s_waitcnt lgkmcnt(0)" ::: "memory"); \
    __builtin_amdgcn_sched_barrier(0);                 \
  } while (0)

// ---------------------------------------------------------------- normalize
__global__ __launch_bounds__(256) void normalize_kernel(
    const float* __restrict__ in, unsigned int* __restrict__ outp) {
  const int row = blockIdx.x;
  const int t = threadIdx.x;  // 256 threads x 4 floats
  const float4 v = ((const float4*)(in + (size_t)row * DIM))[t];
  float ss = v.x * v.x + v.y * v.y + v.z * v.z + v.w * v.w;
#pragma unroll
  for (int s = 1; s < 64; s <<= 1) ss += __shfl_xor(ss, s, 64);
  __shared__ float wsum[4];
  const int wave = t >> 6, lane = t & 63;
  if (lane == 0) wsum[wave] = ss;
  __syncthreads();
  const float tot = wsum[0] + wsum[1] + wsum[2] + wsum[3];
  const float scale = 16.f / fmaxf(sqrtf(tot), 1e-12f);
  unsigned int p = __builtin_amdgcn_cvt_pk_fp8_f32(v.x * scale, v.y * scale, 0, false);
  p = __builtin_amdgcn_cvt_pk_fp8_f32(v.z * scale, v.w * scale, p, true);
  outp[(size_t)row * (DIM / 4) + t] = p;
}

// lane reads logical granules 2q,2q+1 of its slot; x0 = swizzled byte offset,
// second granule at x0^16 (since (2q+1)^k == (2q^k)^1).
#define READ_FRAG(dst, base, off)                                     \
  do {                                                                \
    i32x4 _lo = *(const i32x4*)((base) + (off) + x0);                 \
    i32x4 _hi = *(const i32x4*)((base) + (off) + (x0 ^ 16));          \
    dst = __builtin_shufflevector(_lo, _hi, 0, 1, 2, 3, 4, 5, 6, 7);  \
  } while (0)

#define MFMA_PAIR(NI0)                                                        \
  do {                                                                        \
    __builtin_amdgcn_s_setprio(1);                                            \
    _Pragma("unroll") for (int mi = 0; mi < 4; ++mi) {                        \
      _Pragma("unroll") for (int ni = (NI0); ni < (NI0) + 2; ++ni) {          \
        acc[mi][ni] = __builtin_amdgcn_mfma_scale_f32_16x16x128_f8f6f4(       \
            afr[mi], bfr[ni], acc[mi][ni], 0, 0,                              \
            0, 0x7F7F7F7F, 0, 0x7F7F7F7F); /* unit e8m0 scales */             \
      }                                                                       \
    }                                                                         \
    __builtin_amdgcn_s_setprio(0);                                            \
  } while (0)

#define STAGE_A(buf, k0)                                           \
  do {                                                             \
    _Pragma("unroll") for (int r = 0; r < 4; ++r)                  \
        async16(FA + a_src[r] + (k0), (char*)(buf) + st_dst[r]);   \
  } while (0)
#define STAGE_BLO(buf, k0)                                         \
  do {                                                             \
    _Pragma("unroll") for (int r = 0; r < 2; ++r)                  \
        async16(FB + b_src[r] + (k0), (char*)(buf) + st_dst[r]);   \
  } while (0)
#define STAGE_BHI(buf, k0)                                         \
  do {                                                             \
    _Pragma("unroll") for (int r = 2; r < 4; ++r)                  \
        async16(FB + b_src[r] + (k0), (char*)(buf) + st_dst[r]);   \
  } while (0)

// -------------------------------------------------- Gram row/col-max GEMM
__global__ __launch_bounds__(256, 2) void gemm_rowmax(
    const unsigned char* __restrict__ F, float* __restrict__ partial) {
  // XCD-chunked bijective swizzle (8256 % 8 == 0), then triangular decode
  int bid = blockIdx.x;
  bid = (bid & 7) * (NBLK / 8) + (bid >> 3);
  double disc = (double)(2 * NT + 1) * (2 * NT + 1) - 8.0 * (double)bid;
  int it = (int)(((2 * NT + 1) - sqrt(disc)) * 0.5);
  if (it > NT - 1) it = NT - 1;
  while (it > 0 && it * NT - it * (it - 1) / 2 > bid) --it;
  while ((it + 1) * NT - (it + 1) * it / 2 <= bid) ++it;
  const int jt = it + (bid - (it * NT - it * (it - 1) / 2));

  __shared__ __align__(16) unsigned char sA[2][BT * BKB];  // 2 x 16 KiB
  __shared__ __align__(16) unsigned char sB[2][BT * BKB];  // 2 x 16 KiB
  __shared__ float red[BT][2];
  __shared__ float redc[BT][2];

  const int ibase = it * BT, jbase = jt * BT;
  const int tid = threadIdx.x;
  const int wave = tid >> 6, lane = tid & 63;
  const int wi = wave >> 1, wj = wave & 1;  // 2x2 wave grid, 64x64 each
  const int quad = lane >> 4, r16 = lane & 15;

  const unsigned char* FA = F + (size_t)ibase * DIM;
  const unsigned char* FB = F + (size_t)jbase * DIM;

  // ---- precomputed staging addresses (per-thread src, wave-uniform dst)
  // LDS slot s holds logical granule g at physical position g^(s&7).
  unsigned int a_src[4], b_src[4], st_dst[4];
#pragma unroll
  for (int r = 0; r < 4; ++r) {
    const int flat = r * 256 + tid;  // physical granule index [0,1024)
    const int slot = flat >> 3;
    const int lg = (flat & 7) ^ (slot & 7);
    a_src[r] = (unsigned int)slot * DIM + lg * 16;  // A: slot == row
    // B slot->row: lo slots 0-63 -> rows {0-31,64-95}; hi 64-127 -> rest
    const int grow =
        ((slot >> 6) & 1) * 32 + (slot & 31) + ((slot >> 5) & 1) * 64;
    b_src[r] = (unsigned int)grow * DIM + lg * 16;
    st_dst[r] = (unsigned int)(r * 256 + (tid & ~63)) * 16;
  }

  // ---- precomputed fragment read offsets (loop-invariant)
  const int x0 = ((2 * quad) ^ (r16 & 7)) << 4;
  const unsigned int a_rd = (unsigned int)(wi * 64 + r16) * BKB;  // + mi*2048
  unsigned int b_rd[4];
#pragma unroll
  for (int ni = 0; ni < 4; ++ni) {
    const int lr = wj * 64 + ni * 16 + r16;  // local B row
    const int bs = (lr & 31) | (((lr >> 6) & 1) << 5) | (((lr >> 5) & 1) << 6);
    b_rd[ni] = (unsigned int)bs * BKB;
  }

  f32x4 acc[4][4] = {};  // [mi][ni] 16x16 tiles (AGPR-resident)
  i32x8 afr[4], bfr[4];

  // prologue: stage tile 0 (FIFO: A x4, B-lo x2, B-hi x2 = 8 in flight)
  STAGE_A(sA[0], 0);
  STAGE_BLO(sB[0], 0);
  STAGE_BHI(sB[0], 0);

#pragma unroll 1
  for (int kt = 0; kt < NKT - 1; ++kt) {
    const unsigned char* cA = sA[kt & 1];
    const unsigned char* cB = sB[kt & 1];
    unsigned char* nA = sA[(kt + 1) & 1];
    unsigned char* nB = sB[(kt + 1) & 1];
    const int k0n = (kt + 1) * BKB;

    // ---- phase 1: needs A(T)+B-lo(T); prefetch A(T+1)
    WAIT_VM(2);  // drains A(T) x4 + B-lo(T) x2
    S_BAR();
#pragma unroll
    for (int mi = 0; mi < 4; ++mi) READ_FRAG(afr[mi], cA, a_rd + mi * 2048);
    READ_FRAG(bfr[0], cB, b_rd[0]);
    READ_FRAG(bfr[1], cB, b_rd[1]);
    STAGE_A(nA, k0n);  // in flight: B-hi(T) 2 + A(T+1) 4 = 6
    WAIT_LGKM();
    MFMA_PAIR(0);
    // ---- phase 2: needs B-hi(T); prefetch B(T+1)
    WAIT_VM(4);  // drains B-hi(T) x2
    S_BAR();
    READ_FRAG(bfr[2], cB, b_rd[2]);
    READ_FRAG(bfr[3], cB, b_rd[3]);
    STAGE_BLO(nB, k0n);
    STAGE_BHI(nB, k0n);  // in flight: A(T+1) 4 + B(T+1) 4 = 8
    WAIT_LGKM();
    MFMA_PAIR(2);
  }

  // ---- final K-tile (no prefetch; drain 2 -> 0)
  {
    const unsigned char* cA = sA[(NKT - 1) & 1];
    const unsigned char* cB = sB[(NKT - 1) & 1];
    WAIT_VM(2);
    S_BAR();
#pragma unroll
    for (int mi = 0; mi < 4; ++mi) READ_FRAG(afr[mi], cA, a_rd + mi * 2048);
    READ_FRAG(bfr[0], cB, b_rd[0]);
    READ_FRAG(bfr[1], cB, b_rd[1]);
    WAIT_LGKM();
    MFMA_PAIR(0);
    WAIT_VM(0);
    S_BAR();
    READ_FRAG(bfr[2], cB, b_rd[2]);
    READ_FRAG(bfr[3], cB, b_rd[3]);
    WAIT_LGKM();
    MFMA_PAIR(2);
  }

  // ---------------- epilogue (R9 verbatim): row/col max
  // C/D layout (16x16): col = lane&15, row = quad*4 + reg.
#pragma unroll
  for (int mi = 0; mi < 4; ++mi) {
#pragma unroll
    for (int r = 0; r < 4; ++r) {
      const int rl = wi * 64 + mi * 16 + quad * 4 + r;
      const int rowg = ibase + rl;
      float m = -INFINITY;
#pragma unroll
      for (int ni = 0; ni < 4; ++ni) {
        const int colg = jbase + wj * 64 + ni * 16 + r16;
        const float v = acc[mi][ni][r];
        m = (rowg == colg) ? m : fmaxf(m, v);
      }
#pragma unroll
      for (int s = 1; s < 16; s <<= 1) m = fmaxf(m, __shfl_xor(m, s, 64));
      if (r16 == 0) red[rl][wj] = m;
    }
  }
  if (it != jt) {  // col-max (off-diagonal tiles: no diag elements present)
#pragma unroll
    for (int ni = 0; ni < 4; ++ni) {
      float m = -INFINITY;
#pragma unroll
      for (int mi = 0; mi < 4; ++mi)
#pragma unroll
        for (int r = 0; r < 4; ++r) m = fmaxf(m, acc[mi][ni][r]);
      m = fmaxf(m, __shfl_xor(m, 16, 64));  // reduce across quads
      m = fmaxf(m, __shfl_xor(m, 32, 64));
      if (quad == 0) redc[wj * 64 + ni * 16 + r16][wi] = m;
    }
  }
  __syncthreads();
  if (tid < BT) {
    partial[(size_t)jt * N_ROWS + ibase + tid] = fmaxf(red[tid][0], red[tid][1]);
  } else if (it != jt) {
    const int c = tid - BT;
    partial[(size_t)it * N_ROWS + jbase + c] = fmaxf(redc[c][0], redc[c][1]);
  }
}

// ------------------------------------------------------------- reductions
__global__ __launch_bounds__(256) void row_reduce(
    const float* __restrict__ partial, float* __restrict__ blocksum) {
  const int r = blockIdx.x * 256 + threadIdx.x;
  float m = -INFINITY;
  for (int p = 0; p < NT; ++p)
    m = fmaxf(m, partial[(size_t)p * N_ROWS + r]);
  // raw dot carries x256 (features scaled x16): 2 - 2*(m/256) = 2 - m/128
  const float d2 = fmaxf(2.f - m * (1.f / 128.f), 0.f);
  float term = logf(sqrtf(d2) + 1e-8f);
#pragma unroll
  for (int s = 1; s < 64; s <<= 1) term += __shfl_xor(term, s, 64);
  __shared__ float wsum[4];
  const int wave = threadIdx.x >> 6, lane = threadIdx.x & 63;
  if (lane == 0) wsum[wave] = term;
  __syncthreads();
  if (threadIdx.x == 0)
    blocksum[blockIdx.x] = wsum[0] + wsum[1] + wsum[2] + wsum[3];
}

__global__ void finalize(const float* __restrict__ blocksum,
                         float* __restrict__ out) {
  float v = blocksum[threadIdx.x];
#pragma unroll
  for (int s = 1; s < 64; s <<= 1) v += __shfl_xor(v, s, 64);
  if (threadIdx.x == 0) out[0] = -v / (float)N_ROWS;
}

// ---------------------------------------------------------------- launcher
extern "C" void kernel_launch(void* const* d_in, const int* in_sizes, int n_in,
                              void* d_out, int out_size, void* d_ws, size_t ws_size,
                              hipStream_t stream) {
  const float* feats = (const float*)d_in[0];
  float* out = (float*)d_out;
  char* ws = (char*)d_ws;

  // ws: [0,16MB) fp8 features; [16MB,24MB) partial [128][16384] f32; then sums.
  unsigned char* f8 = (unsigned char*)ws;
  float* partial = (float*)(ws + (size_t)N_ROWS * DIM);
  float* blocksum =
      (float*)(ws + (size_t)N_ROWS * DIM + (size_t)NT * N_ROWS * 4);

  normalize_kernel<<<N_ROWS, 256, 0, stream>>>(feats, (unsigned int*)f8);
  gemm_rowmax<<<NBLK, 256, 0, stream>>>(f8, partial);
  row_reduce<<<N_ROWS / 256, 256, 0, stream>>>(partial, blocksum);
  finalize<<<1, 64, 0, stream>>>(blocksum, out);
}

// Round 4
// 281.226 us; speedup vs baseline: 1.9252x; 1.1147x over previous
//
#include <hip/hip_runtime.h>
#include <math.h>

// KoLeo loss: dist_i = sqrt(2 - 2*max_{j!=i} <fhat_i, fhat_j>); loss = -mean(log(dist+1e-8))
// R13: 256^2 block tile, 16 waves of 64x64 (R9's per-wave budget: 64 VGPR +
// 64 AGPR -> 4 waves/SIMD), 1024 threads, full 128 KiB LDS double-buffer,
// minimal counted 2-phase schedule. Resource model (R9/R10/R12 evidence):
// every structure pins MFMA busy-time at the 59 us floor; the cap is the
// staging path -- 128^2 tiles stage 7.8 uB/FLOP ~= per-CU L2 peak (56 B/cy),
// co-critical with MFMA. 256^2 halves that (3.9 uB/FLOP -> 4.2 MB/CU, ~35 us,
// hidden); new ceiling is the LDS read pipe (16 waves x 16 ds_read_b128 per
// K-tile ~ 3072 cy vs MFMA 2208 cy -> ~95 us). Schedule per K-tile:
//   STAGE(next) ; vmcnt(4) [prev stage, issued a full iter ago -> instant]
//   barrier ; frag reads + 16 MFMA ; lgkm ; barrier
// Never vmcnt(0) in the main loop. R10's failure was per-phase waits exposed
// serially at 2 waves/SIMD -- here 4 waves/SIMD interleave reads with MFMA.
// 16B-granule XOR swizzle (granule g of row r at phys g^(r&7)), linear
// gload_lds dest + pre-swizzled source (rule #21). red/redc alias dead LDS.
// Features pre-scaled x16 before e4m3 cast; raw dots carry x256, folded out in
// row_reduce (max is monotone). Each tile yields row-max AND col-max.

#define N_ROWS 16384
#define DIM 1024
#define BT 256
#define BKB 128                   // K bytes per tile (one K=128 MFMA)
#define NKT (DIM / BKB)           // 8
#define NT (N_ROWS / BT)          // 64
#define NBLK (NT * (NT + 1) / 2)  // 2080 (divisible by 8 -> XCD swizzle)

typedef int   i32x4 __attribute__((ext_vector_type(4)));
typedef int   i32x8 __attribute__((ext_vector_type(8)));
typedef float f32x4 __attribute__((ext_vector_type(4)));

__device__ __forceinline__ void async16(const void* g, void* l) {
  __builtin_amdgcn_global_load_lds(
      (__attribute__((address_space(1))) const void*)g,
      (__attribute__((address_space(3))) void*)l, 16, 0, 0);
}

// Raw barrier with compile-time motion fences (rule #18).
#define S_BAR()                        \
  do {                                 \
    __builtin_amdgcn_sched_barrier(0); \
    __builtin_amdgcn_s_barrier();      \
    __builtin_amdgcn_sched_barrier(0); \
  } while (0)
#define WAIT_VM(N) asm volatile("s_waitcnt vmcnt(" #N ")" ::: "memory")
#define WAIT_LGKM()                                    \
  do {                                                 \
    asm volatile("s_waitcnt lgkmcnt(0)" ::: "memory"); \
    __builtin_amdgcn_sched_barrier(0);                 \
  } while (0)

// ---------------------------------------------------------------- normalize
__global__ __launch_bounds__(256) void normalize_kernel(
    const float* __restrict__ in, unsigned int* __restrict__ outp) {
  const int row = blockIdx.x;
  const int t = threadIdx.x;  // 256 threads x 4 floats
  const float4 v = ((const float4*)(in + (size_t)row * DIM))[t];
  float ss = v.x * v.x + v.y * v.y + v.z * v.z + v.w * v.w;
#pragma unroll
  for (int s = 1; s < 64; s <<= 1) ss += __shfl_xor(ss, s, 64);
  __shared__ float wsum[4];
  const int wave = t >> 6, lane = t & 63;
  if (lane == 0) wsum[wave] = ss;
  __syncthreads();
  const float tot = wsum[0] + wsum[1] + wsum[2] + wsum[3];
  const float scale = 16.f / fmaxf(sqrtf(tot), 1e-12f);
  unsigned int p = __builtin_amdgcn_cvt_pk_fp8_f32(v.x * scale, v.y * scale, 0, false);
  p = __builtin_amdgcn_cvt_pk_fp8_f32(v.z * scale, v.w * scale, p, true);
  outp[(size_t)row * (DIM / 4) + t] = p;
}

// lane reads logical granules 2q,2q+1 of its slot; x0 = swizzled byte offset,
// second granule at x0^16 (since (2q+1)^k == (2q^k)^1).
#define READ_FRAG(dst, base, off)                                    \
  do {                                                               \
    i32x4 _lo = *(const i32x4*)((base) + (off) + x0);                \
    i32x4 _hi = *(const i32x4*)((base) + (off) + (x0 ^ 16));         \
    dst = __builtin_shufflevector(_lo, _hi, 0, 1, 2, 3, 4, 5, 6, 7); \
  } while (0)

// stage both panels' next K-slab: 4 gload_lds per wave (2 A + 2 B)
#define STAGE(bi, k0)                                                 \
  do {                                                                \
    _Pragma("unroll") for (int r = 0; r < 2; ++r) {                   \
      async16(FA + (k0) + srcoff[r], &lds[bi][0][dst_u + r * 16384]); \
      async16(FB + (k0) + srcoff[r], &lds[bi][1][dst_u + r * 16384]); \
    }                                                                 \
  } while (0)

// -------------------------------------------------- Gram row/col-max GEMM
__global__ __launch_bounds__(1024, 4) void gemm_rowmax(
    const unsigned char* __restrict__ F, float* __restrict__ partial) {
  // XCD-chunked bijective swizzle (2080 % 8 == 0), then triangular decode
  int bid = blockIdx.x;
  bid = (bid & 7) * (NBLK / 8) + (bid >> 3);
  double disc = (double)(2 * NT + 1) * (2 * NT + 1) - 8.0 * (double)bid;
  int it = (int)(((2 * NT + 1) - sqrt(disc)) * 0.5);
  if (it > NT - 1) it = NT - 1;
  while (it > 0 && it * NT - it * (it - 1) / 2 > bid) --it;
  while ((it + 1) * NT - (it + 1) * it / 2 <= bid) ++it;
  const int jt = it + (bid - (it * NT - it * (it - 1) / 2));

  __shared__ __align__(16) unsigned char lds[2][2][BT * BKB];  // 128 KiB

  const int ibase = it * BT, jbase = jt * BT;
  const int tid = threadIdx.x;
  const int wave = tid >> 6, lane = tid & 63;
  const int wi = wave >> 2, wj = wave & 3;  // 4x4 wave grid, 64x64 each
  const int quad = lane >> 4, r16 = lane & 15;

  const unsigned char* FA = F + (size_t)ibase * DIM;
  const unsigned char* FB = F + (size_t)jbase * DIM;

  // ---- staging addresses: granule flat = r*1024 + tid; slot = flat>>3
  // (row 0..255); logical granule lg = (flat&7)^(slot&7) -- constant per
  // thread since 1024 % 8 == 0. Per-thread src offset affine in r.
  const unsigned int lg16 = (unsigned int)(((tid & 7) ^ ((tid >> 3) & 7)) << 4);
  unsigned int srcoff[2];
  srcoff[0] = (unsigned int)(tid >> 3) * 1024u + lg16;
  srcoff[1] = srcoff[0] + 131072u;  // +128 rows
  const unsigned int dst_u = (unsigned int)(tid & ~63) * 16u;

  // ---- fragment read offsets (loop-invariant)
  const int x0 = ((2 * quad) ^ (r16 & 7)) << 4;
  const unsigned int a_rd = (unsigned int)(wi * 64 + r16) * BKB;  // + mi*2048
  const unsigned int b_rd = (unsigned int)(wj * 64 + r16) * BKB;  // + ni*2048

  f32x4 acc[4][4] = {};  // [mi][ni] 16x16 tiles (AGPR-resident)
  i32x8 afr[4], bfr;

  STAGE(0, 0);  // prologue: 4 loads in flight

#pragma unroll 1
  for (int kt = 0; kt < NKT; ++kt) {
    const int cur = kt & 1;
    if (kt < NKT - 1) {
      STAGE(cur ^ 1, (kt + 1) * BKB);  // issue next; 8 in flight
      WAIT_VM(4);                      // previous stage landed (issued ~1 iter ago)
    } else {
      WAIT_VM(0);  // epilogue drain
    }
    S_BAR();
    const unsigned char* cA = &lds[cur][0][0];
    const unsigned char* cB = &lds[cur][1][0];
#pragma unroll
    for (int mi = 0; mi < 4; ++mi) READ_FRAG(afr[mi], cA, a_rd + mi * 2048);
#pragma unroll
    for (int ni = 0; ni < 4; ++ni) {
      READ_FRAG(bfr, cB, b_rd + ni * 2048);
#pragma unroll
      for (int mi = 0; mi < 4; ++mi)
        acc[mi][ni] = __builtin_amdgcn_mfma_scale_f32_16x16x128_f8f6f4(
            afr[mi], bfr, acc[mi][ni], 0, 0,  // cbsz=0 (fp8), blgp=0 (fp8)
            0, 0x7F7F7F7F, 0, 0x7F7F7F7F);    // unit e8m0 scales
    }
    WAIT_LGKM();  // reads of lds[cur] complete before releasing the buffer
    S_BAR();
  }

  // ---------------- epilogue: row/col max (alias dead staging LDS --
  // lds[0] last read at kt=6, guarded by that iteration's end barrier)
  float(*red)[4] = (float(*)[4]) & lds[0][0][0];           // [256][4] over wj
  float(*redc)[4] = (float(*)[4])(&lds[0][0][0] + 4096);   // [256][4] over wi

  // C/D layout (16x16): col = lane&15, row = quad*4 + reg.
#pragma unroll
  for (int mi = 0; mi < 4; ++mi) {
#pragma unroll
    for (int r = 0; r < 4; ++r) {
      const int rl = wi * 64 + mi * 16 + quad * 4 + r;
      const int rowg = ibase + rl;
      float m = -INFINITY;
#pragma unroll
      for (int ni = 0; ni < 4; ++ni) {
        const int colg = jbase + wj * 64 + ni * 16 + r16;
        const float v = acc[mi][ni][r];
        m = (rowg == colg) ? m : fmaxf(m, v);
      }
#pragma unroll
      for (int s = 1; s < 16; s <<= 1) m = fmaxf(m, __shfl_xor(m, s, 64));
      if (r16 == 0) red[rl][wj] = m;
    }
  }
  if (it != jt) {  // col-max (off-diagonal tiles: no diag elements present)
#pragma unroll
    for (int ni = 0; ni < 4; ++ni) {
      float m = -INFINITY;
#pragma unroll
      for (int mi = 0; mi < 4; ++mi)
#pragma unroll
        for (int r = 0; r < 4; ++r) m = fmaxf(m, acc[mi][ni][r]);
      m = fmaxf(m, __shfl_xor(m, 16, 64));  // reduce across quads
      m = fmaxf(m, __shfl_xor(m, 32, 64));
      if (quad == 0) redc[wj * 64 + ni * 16 + r16][wi] = m;
    }
  }
  __syncthreads();
  if (tid < BT) {
    const float a = fmaxf(red[tid][0], red[tid][1]);
    const float b = fmaxf(red[tid][2], red[tid][3]);
    partial[(size_t)jt * N_ROWS + ibase + tid] = fmaxf(a, b);
  } else if (tid < 2 * BT && it != jt) {
    const int c = tid - BT;
    const float a = fmaxf(redc[c][0], redc[c][1]);
    const float b = fmaxf(redc[c][2], redc[c][3]);
    partial[(size_t)it * N_ROWS + jbase + c] = fmaxf(a, b);
  }
}

// ------------------------------------------------------------- reductions
__global__ __launch_bounds__(256) void row_reduce(
    const float* __restrict__ partial, float* __restrict__ blocksum) {
  const int r = blockIdx.x * 256 + threadIdx.x;
  float m = -INFINITY;
  for (int p = 0; p < NT; ++p)
    m = fmaxf(m, partial[(size_t)p * N_ROWS + r]);
  // raw dot carries x256 (features scaled x16): 2 - 2*(m/256) = 2 - m/128
  const float d2 = fmaxf(2.f - m * (1.f / 128.f), 0.f);
  float term = logf(sqrtf(d2) + 1e-8f);
#pragma unroll
  for (int s = 1; s < 64; s <<= 1) term += __shfl_xor(term, s, 64);
  __shared__ float wsum[4];
  const int wave = threadIdx.x >> 6, lane = threadIdx.x & 63;
  if (lane == 0) wsum[wave] = term;
  __syncthreads();
  if (threadIdx.x == 0)
    blocksum[blockIdx.x] = wsum[0] + wsum[1] + wsum[2] + wsum[3];
}

__global__ void finalize(const float* __restrict__ blocksum,
                         float* __restrict__ out) {
  float v = blocksum[threadIdx.x];
#pragma unroll
  for (int s = 1; s < 64; s <<= 1) v += __shfl_xor(v, s, 64);
  if (threadIdx.x == 0) out[0] = -v / (float)N_ROWS;
}

// ---------------------------------------------------------------- launcher
extern "C" void kernel_launch(void* const* d_in, const int* in_sizes, int n_in,
                              void* d_out, int out_size, void* d_ws, size_t ws_size,
                              hipStream_t stream) {
  const float* feats = (const float*)d_in[0];
  float* out = (float*)d_out;
  char* ws = (char*)d_ws;

  // ws: [0,16MB) fp8 features; [16MB,20MB) partial [64][16384] f32; then sums.
  unsigned char* f8 = (unsigned char*)ws;
  float* partial = (float*)(ws + (size_t)N_ROWS * DIM);
  float* blocksum =
      (float*)(ws + (size_t)N_ROWS * DIM + (size_t)NT * N_ROWS * 4);

  normalize_kernel<<<N_ROWS, 256, 0, stream>>>(feats, (unsigned int*)f8);
  gemm_rowmax<<<NBLK, 1024, 0, stream>>>(f8, partial);
  row_reduce<<<N_ROWS / 256, 256, 0, stream>>>(partial, blocksum);
  finalize<<<1, 64, 0, stream>>>(blocksum, out);
}